// Round 1
// baseline (3144.158 us; speedup 1.0000x reference)
//
#include <hip/hip_runtime.h>
#include <hip/hip_bf16.h>

// Problem constants (from reference setup_inputs)
#define BB 2
#define NN 4096
#define DD 512
#define EE 16
#define HH 2048
#define CAP 1024   // capacity = int((4096*2)*2.0/16) = 1024
#define NTOK (BB*NN)   // 8192

// ---------------------------------------------------------------------------
// Kernel 1: gating — logits = x @ w_gating, softmax, top-2, normalized gates.
// One wave (64 lanes) per token; 4 tokens per 256-thread block.
// ---------------------------------------------------------------------------
__launch_bounds__(256)
__global__ void gating_kernel(const float* __restrict__ x,
                              const float* __restrict__ wg,
                              int* __restrict__ e1, int* __restrict__ e2,
                              float* __restrict__ g1, float* __restrict__ g2) {
    int wave = threadIdx.x >> 6;
    int lane = threadIdx.x & 63;
    int t = blockIdx.x * 4 + wave;          // token 0..8191
    const float* xp = x + (size_t)t * DD;

    float acc[EE];
#pragma unroll
    for (int e = 0; e < EE; e++) acc[e] = 0.f;

    for (int d = lane; d < DD; d += 64) {
        float xv = xp[d];
        const float* wrow = wg + d * EE;
#pragma unroll
        for (int e = 0; e < EE; e++) acc[e] = fmaf(xv, wrow[e], acc[e]);
    }
    // butterfly reduce across the wave
#pragma unroll
    for (int off = 32; off > 0; off >>= 1) {
#pragma unroll
        for (int e = 0; e < EE; e++) acc[e] += __shfl_xor(acc[e], off, 64);
    }
    if (lane == 0) {
        float m = acc[0];
#pragma unroll
        for (int e = 1; e < EE; e++) m = fmaxf(m, acc[e]);
        float p[EE];
        float s = 0.f;
#pragma unroll
        for (int e = 0; e < EE; e++) { p[e] = __expf(acc[e] - m); s += p[e]; }
        float inv = 1.f / s;
#pragma unroll
        for (int e = 0; e < EE; e++) p[e] *= inv;
        // top-1 (first index wins ties, matching jnp.argmax)
        int i1 = 0; float v1 = p[0];
#pragma unroll
        for (int e = 1; e < EE; e++) if (p[e] > v1) { v1 = p[e]; i1 = e; }
        // top-2 excluding i1
        int i2 = (i1 == 0) ? 1 : 0; float v2 = p[i2];
#pragma unroll
        for (int e = 0; e < EE; e++)
            if (e != i1 && p[e] > v2) { v2 = p[e]; i2 = e; }
        float denom = v1 + v2 + 1e-9f;
        e1[t] = i1; e2[t] = i2;
        g1[t] = v1 / denom; g2[t] = v2 / denom;
    }
}

// ---------------------------------------------------------------------------
// Kernel 2: per-(b,e) exclusive scan over token order -> positions + capacity
// drop. 32 blocks (b*e), 256 threads, 16 consecutive tokens per thread.
// p1/p2 hold the slot index, or -1 if dropped. Exactly one block writes each.
// ---------------------------------------------------------------------------
__launch_bounds__(256)
__global__ void scan_kernel(const int* __restrict__ e1, const int* __restrict__ e2,
                            int* __restrict__ p1, int* __restrict__ p2) {
    int b = blockIdx.x / EE;
    int e = blockIdx.x % EE;
    int tid = threadIdx.x;
    const int base = b * NN;
    int n0 = tid * 16;

    unsigned m1 = 0, m2 = 0;
    int c1 = 0, c2 = 0;
#pragma unroll
    for (int j = 0; j < 16; j++) {
        int n = n0 + j;
        if (e1[base + n] == e) { m1 |= 1u << j; c1++; }
        if (e2[base + n] == e) { m2 |= 1u << j; c2++; }
    }
    __shared__ int s1[256], s2[256];
    s1[tid] = c1; s2[tid] = c2;
    __syncthreads();
    // Hillis-Steele inclusive scan
    for (int off = 1; off < 256; off <<= 1) {
        int a1 = (tid >= off) ? s1[tid - off] : 0;
        int a2 = (tid >= off) ? s2[tid - off] : 0;
        __syncthreads();
        s1[tid] += a1; s2[tid] += a2;
        __syncthreads();
    }
    int total1 = s1[255];
    int kept1 = min(total1, CAP);     // mask_1_count after capacity truncation
    int ex1 = s1[tid] - c1;           // exclusive prefix (top-1)
    int ex2 = s2[tid] - c2 + kept1;   // top-2 positions start after kept top-1
#pragma unroll
    for (int j = 0; j < 16; j++) {
        int n = n0 + j;
        if (m1 & (1u << j)) { p1[base + n] = (ex1 < CAP) ? ex1 : -1; ex1++; }
        if (m2 & (1u << j)) { p2[base + n] = (ex2 < CAP) ? ex2 : -1; ex2++; }
    }
}

// ---------------------------------------------------------------------------
// Kernel 3: scatter tokens into expert buckets (dispatch einsum as a scatter).
// One 128-thread block per token; float4 copy of 512 floats to <=2 slots.
// ---------------------------------------------------------------------------
__launch_bounds__(128)
__global__ void scatter_kernel(const float* __restrict__ x,
                               const int* __restrict__ e1, const int* __restrict__ e2,
                               const int* __restrict__ p1, const int* __restrict__ p2,
                               float* __restrict__ ein) {
    int t = blockIdx.x;
    int b = t / NN;
    int tid = threadIdx.x;
    float4 v = ((const float4*)(x + (size_t)t * DD))[tid];
    int q1 = p1[t];
    if (q1 >= 0) {
        float4* dst = (float4*)(ein + (((size_t)e1[t] * BB + b) * CAP + q1) * DD);
        dst[tid] = v;
    }
    int q2 = p2[t];
    if (q2 >= 0) {
        float4* dst = (float4*)(ein + (((size_t)e2[t] * BB + b) * CAP + q2) * DD);
        dst[tid] = v;
    }
}

// ---------------------------------------------------------------------------
// Kernel 4: classic f32 SGEMM, row-major A[M,K] * B[K,N] -> C[M,N].
// 64x64 tile, BK=16, 256 threads, 4x4 accum/thread. Optional fused ReLU.
// LDS rows padded to 68 floats: 16B-aligned, <=2-way bank aliasing (free).
// ---------------------------------------------------------------------------
template <int RELU>
__launch_bounds__(256)
__global__ void gemm_rrr(const float* __restrict__ A, const float* __restrict__ Bm,
                         float* __restrict__ Cm, int M, int Nc, int K) {
    __shared__ float As[16][68];   // [k][m] (transposed store)
    __shared__ float Bs[16][68];   // [k][n]
    int tid = threadIdx.x;
    int tx = tid & 15, ty = tid >> 4;
    int row0 = blockIdx.y * 64;
    int col0 = blockIdx.x * 64;

    int arow = tid >> 2, ac4 = (tid & 3) * 4;   // A: 64 rows x 4 float4
    int brow = tid >> 4, bc4 = (tid & 15) * 4;  // B: 16 rows x 16 float4

    float acc[4][4] = {};
    for (int k0 = 0; k0 < K; k0 += 16) {
        float4 av = *(const float4*)(A + (size_t)(row0 + arow) * K + k0 + ac4);
        float4 bv = *(const float4*)(Bm + (size_t)(k0 + brow) * Nc + col0 + bc4);
        As[ac4 + 0][arow] = av.x;
        As[ac4 + 1][arow] = av.y;
        As[ac4 + 2][arow] = av.z;
        As[ac4 + 3][arow] = av.w;
        *(float4*)&Bs[brow][bc4] = bv;
        __syncthreads();
#pragma unroll
        for (int kk = 0; kk < 16; kk++) {
            float4 a4 = *(const float4*)&As[kk][ty * 4];
            float4 b4 = *(const float4*)&Bs[kk][tx * 4];
            float a[4] = {a4.x, a4.y, a4.z, a4.w};
            float b[4] = {b4.x, b4.y, b4.z, b4.w};
#pragma unroll
            for (int i = 0; i < 4; i++)
#pragma unroll
                for (int j = 0; j < 4; j++)
                    acc[i][j] = fmaf(a[i], b[j], acc[i][j]);
        }
        __syncthreads();
    }
#pragma unroll
    for (int i = 0; i < 4; i++) {
        float4 o;
        o.x = acc[i][0]; o.y = acc[i][1]; o.z = acc[i][2]; o.w = acc[i][3];
        if (RELU) {
            o.x = fmaxf(o.x, 0.f); o.y = fmaxf(o.y, 0.f);
            o.z = fmaxf(o.z, 0.f); o.w = fmaxf(o.w, 0.f);
        }
        *(float4*)(Cm + (size_t)(row0 + ty * 4 + i) * Nc + col0 + tx * 4) = o;
    }
}

// ---------------------------------------------------------------------------
// Kernel 5: combine — gather each token's <=2 expert outputs, weighted.
// ---------------------------------------------------------------------------
__launch_bounds__(128)
__global__ void combine_kernel(const float* __restrict__ eo,
                               const int* __restrict__ e1, const int* __restrict__ e2,
                               const int* __restrict__ p1, const int* __restrict__ p2,
                               const float* __restrict__ g1, const float* __restrict__ g2,
                               float* __restrict__ out) {
    int t = blockIdx.x;
    int b = t / NN;
    int tid = threadIdx.x;
    float4 r = make_float4(0.f, 0.f, 0.f, 0.f);
    int q1 = p1[t];
    if (q1 >= 0) {
        float4 v = ((const float4*)(eo + (((size_t)e1[t] * BB + b) * CAP + q1) * DD))[tid];
        float g = g1[t];
        r.x = fmaf(g, v.x, r.x); r.y = fmaf(g, v.y, r.y);
        r.z = fmaf(g, v.z, r.z); r.w = fmaf(g, v.w, r.w);
    }
    int q2 = p2[t];
    if (q2 >= 0) {
        float4 v = ((const float4*)(eo + (((size_t)e2[t] * BB + b) * CAP + q2) * DD))[tid];
        float g = g2[t];
        r.x = fmaf(g, v.x, r.x); r.y = fmaf(g, v.y, r.y);
        r.z = fmaf(g, v.z, r.z); r.w = fmaf(g, v.w, r.w);
    }
    ((float4*)(out + (size_t)t * DD))[tid] = r;
}

// ---------------------------------------------------------------------------
// Launch: gating -> scan -> scatter -> per-expert (GEMM1+ReLU, GEMM2) -> combine
// Workspace layout (bytes):
//   0        e1 (8192 i32)      32768   e2
//   65536    p1                 98304   p2
//   131072   g1 (f32)           163840  g2
//   196608   expert_inputs  [16][2][1024][512] f32 = 67,108,864
//   67305472 expert_outputs [16][2][1024][512] f32 = 67,108,864
//   134414336 hidden (one expert) [2048][2048] f32  = 16,777,216
//   total ≈ 151.2 MB
// ---------------------------------------------------------------------------
extern "C" void kernel_launch(void* const* d_in, const int* in_sizes, int n_in,
                              void* d_out, int out_size, void* d_ws, size_t ws_size,
                              hipStream_t stream) {
    const float* x  = (const float*)d_in[0];
    const float* wg = (const float*)d_in[1];
    const float* w1 = (const float*)d_in[2];
    const float* w2 = (const float*)d_in[3];
    float* out = (float*)d_out;

    char* ws = (char*)d_ws;
    int*   e1   = (int*)(ws + 0);
    int*   e2   = (int*)(ws + 32768);
    int*   p1   = (int*)(ws + 65536);
    int*   p2   = (int*)(ws + 98304);
    float* g1   = (float*)(ws + 131072);
    float* g2   = (float*)(ws + 163840);
    float* ein  = (float*)(ws + 196608);
    float* eout = (float*)(ws + 196608 + 67108864ull);
    float* hid  = (float*)(ws + 196608 + 2ull * 67108864ull);

    // zero expert input buckets (ws is poisoned 0xAA before every call)
    hipMemsetAsync(ein, 0, 67108864ull, stream);

    gating_kernel<<<NTOK / 4, 256, 0, stream>>>(x, wg, e1, e2, g1, g2);
    scan_kernel<<<BB * EE, 256, 0, stream>>>(e1, e2, p1, p2);
    scatter_kernel<<<NTOK, 128, 0, stream>>>(x, e1, e2, p1, p2, ein);

    for (int e = 0; e < EE; e++) {
        const float* Ae  = ein  + (size_t)e * BB * CAP * DD;   // [2048,512]
        const float* W1e = w1   + (size_t)e * DD * HH;         // [512,2048]
        const float* W2e = w2   + (size_t)e * HH * DD;         // [2048,512]
        float* Oe        = eout + (size_t)e * BB * CAP * DD;   // [2048,512]
        gemm_rrr<1><<<dim3(HH / 64, (BB * CAP) / 64), 256, 0, stream>>>(
            Ae, W1e, hid, BB * CAP, HH, DD);
        gemm_rrr<0><<<dim3(DD / 64, (BB * CAP) / 64), 256, 0, stream>>>(
            hid, W2e, Oe, BB * CAP, DD, HH);
    }

    combine_kernel<<<NTOK, 128, 0, stream>>>(eout, e1, e2, p1, p2, g1, g2, out);
}

// Round 2
// 528.222 us; speedup vs baseline: 5.9523x; 5.9523x over previous
//
#include <hip/hip_runtime.h>

// Problem constants (from reference setup_inputs)
#define BB 2
#define NN 4096
#define DD 512
#define EE 16
#define HH 2048
#define CAP 1024            // capacity = int((4096*2)*2.0/16) = 1024
#define NTOK (BB*NN)        // 8192
#define MM (BB*CAP)         // 2048 = per-expert GEMM M

typedef unsigned short ushort_t;
typedef __attribute__((ext_vector_type(8))) short bf16x8;   // 8 bf16 = 4 VGPRs
typedef __attribute__((ext_vector_type(4))) float floatx4;  // MFMA accumulator

// round-to-nearest-even f32 -> bf16 bit pattern
__device__ __forceinline__ ushort_t f2bf(float f) {
    union { float f; unsigned u; } v; v.f = f;
    unsigned r = v.u + 0x7fffu + ((v.u >> 16) & 1u);
    return (ushort_t)(r >> 16);
}

// async global->LDS, 16B per lane (global_load_lds_dwordx4)
__device__ __forceinline__ void cp16(const void* g, void* l) {
    __builtin_amdgcn_global_load_lds(
        (const __attribute__((address_space(1))) void*)g,
        (__attribute__((address_space(3))) void*)l, 16, 0, 0);
}

// ---------------------------------------------------------------------------
// Kernel 1: gating — logits = x @ w_gating, softmax, top-2, normalized gates.
// One wave per token; 4 tokens per 256-thread block. (f32 exact: expert
// selection must match reference argmax.)
// ---------------------------------------------------------------------------
__launch_bounds__(256)
__global__ void gating_kernel(const float* __restrict__ x,
                              const float* __restrict__ wg,
                              int* __restrict__ e1, int* __restrict__ e2,
                              float* __restrict__ g1, float* __restrict__ g2) {
    int wave = threadIdx.x >> 6;
    int lane = threadIdx.x & 63;
    int t = blockIdx.x * 4 + wave;
    const float* xp = x + (size_t)t * DD;

    float acc[EE];
#pragma unroll
    for (int e = 0; e < EE; e++) acc[e] = 0.f;
    for (int d = lane; d < DD; d += 64) {
        float xv = xp[d];
        const float* wrow = wg + d * EE;
#pragma unroll
        for (int e = 0; e < EE; e++) acc[e] = fmaf(xv, wrow[e], acc[e]);
    }
#pragma unroll
    for (int off = 32; off > 0; off >>= 1) {
#pragma unroll
        for (int e = 0; e < EE; e++) acc[e] += __shfl_xor(acc[e], off, 64);
    }
    if (lane == 0) {
        float m = acc[0];
#pragma unroll
        for (int e = 1; e < EE; e++) m = fmaxf(m, acc[e]);
        float p[EE]; float s = 0.f;
#pragma unroll
        for (int e = 0; e < EE; e++) { p[e] = __expf(acc[e] - m); s += p[e]; }
        float inv = 1.f / s;
#pragma unroll
        for (int e = 0; e < EE; e++) p[e] *= inv;
        int i1 = 0; float v1 = p[0];
#pragma unroll
        for (int e = 1; e < EE; e++) if (p[e] > v1) { v1 = p[e]; i1 = e; }
        int i2 = (i1 == 0) ? 1 : 0; float v2 = p[i2];
#pragma unroll
        for (int e = 0; e < EE; e++)
            if (e != i1 && p[e] > v2) { v2 = p[e]; i2 = e; }
        float denom = v1 + v2 + 1e-9f;
        e1[t] = i1; e2[t] = i2;
        g1[t] = v1 / denom; g2[t] = v2 / denom;
    }
}

// ---------------------------------------------------------------------------
// Kernel 2: per-(b,e) exclusive scan over token order -> slot positions with
// capacity drop (-1). Also writes used[e][b] = number of claimed slots
// (claimed slots are contiguous [0,used)) for GEMM early-exit.
// ---------------------------------------------------------------------------
__launch_bounds__(256)
__global__ void scan_kernel(const int* __restrict__ e1, const int* __restrict__ e2,
                            int* __restrict__ p1, int* __restrict__ p2,
                            int* __restrict__ used) {
    int b = blockIdx.x / EE;
    int e = blockIdx.x % EE;
    int tid = threadIdx.x;
    const int base = b * NN;
    int n0 = tid * 16;

    unsigned m1 = 0, m2 = 0;
    int c1 = 0, c2 = 0;
#pragma unroll
    for (int j = 0; j < 16; j++) {
        int n = n0 + j;
        if (e1[base + n] == e) { m1 |= 1u << j; c1++; }
        if (e2[base + n] == e) { m2 |= 1u << j; c2++; }
    }
    __shared__ int s1[256], s2[256];
    s1[tid] = c1; s2[tid] = c2;
    __syncthreads();
    for (int off = 1; off < 256; off <<= 1) {
        int a1 = (tid >= off) ? s1[tid - off] : 0;
        int a2 = (tid >= off) ? s2[tid - off] : 0;
        __syncthreads();
        s1[tid] += a1; s2[tid] += a2;
        __syncthreads();
    }
    int total1 = s1[255];
    int total2 = s2[255];
    int kept1 = min(total1, CAP);
    int ex1 = s1[tid] - c1;
    int ex2 = s2[tid] - c2 + kept1;
#pragma unroll
    for (int j = 0; j < 16; j++) {
        int n = n0 + j;
        if (m1 & (1u << j)) { p1[base + n] = (ex1 < CAP) ? ex1 : -1; ex1++; }
        if (m2 & (1u << j)) { p2[base + n] = (ex2 < CAP) ? ex2 : -1; ex2++; }
    }
    if (tid == 255) {
        int kept2 = min(total2, max(0, CAP - kept1));
        used[e * BB + b] = kept1 + kept2;
    }
}

// ---------------------------------------------------------------------------
// Kernel 3: scatter tokens (bf16) into expert buckets; record slot->token and
// slot->gate for the fused combine in GEMM2's epilogue.
// ---------------------------------------------------------------------------
__launch_bounds__(128)
__global__ void scatter_kernel(const float* __restrict__ x,
                               const int* __restrict__ e1, const int* __restrict__ e2,
                               const int* __restrict__ p1, const int* __restrict__ p2,
                               const float* __restrict__ g1, const float* __restrict__ g2,
                               ushort_t* __restrict__ ein,
                               int* __restrict__ s2t, float* __restrict__ s2g) {
    int t = blockIdx.x;
    int b = t / NN;
    int tid = threadIdx.x;
    float4 v = ((const float4*)(x + (size_t)t * DD))[tid];
    ushort4 h;
    h.x = f2bf(v.x); h.y = f2bf(v.y); h.z = f2bf(v.z); h.w = f2bf(v.w);
    int q1 = p1[t];
    if (q1 >= 0) {
        int slot = (e1[t] * BB + b) * CAP + q1;
        ((ushort4*)(ein + (size_t)slot * DD))[tid] = h;
        if (tid == 0) { s2t[slot] = t; s2g[slot] = g1[t]; }
    }
    int q2 = p2[t];
    if (q2 >= 0) {
        int slot = (e2[t] * BB + b) * CAP + q2;
        ((ushort4*)(ein + (size_t)slot * DD))[tid] = h;
        if (tid == 0) { s2t[slot] = t; s2g[slot] = g2[t]; }
    }
}

// ---------------------------------------------------------------------------
// Kernel 4: per-expert transpose + bf16 convert: in f32 [E][R][C] -> out bf16
// [E][C][R]. Gives the GEMMs K-contiguous B^T operands for ds_read_b128 /
// global_load_lds staging.
// ---------------------------------------------------------------------------
__global__ void transpose_bf16(const float* __restrict__ in,
                               ushort_t* __restrict__ outp, int R, int C) {
    __shared__ float tile[32][33];
    const float* slab = in + (size_t)blockIdx.z * R * C;
    ushort_t* oslab = outp + (size_t)blockIdx.z * R * C;
    int c0 = blockIdx.x * 32, r0 = blockIdx.y * 32;
    int tx = threadIdx.x, ty = threadIdx.y;   // (32, 8)
#pragma unroll
    for (int j = 0; j < 4; j++)
        tile[ty + j * 8][tx] = slab[(size_t)(r0 + ty + j * 8) * C + c0 + tx];
    __syncthreads();
#pragma unroll
    for (int j = 0; j < 4; j++)
        oslab[(size_t)(c0 + ty + j * 8) * R + r0 + tx] = f2bf(tile[tx][ty + j * 8]);
}

// ---------------------------------------------------------------------------
// Kernel 5: bf16 MFMA GEMM (m97 structure): A[M][K] row-major, Bt[N][K]
// (B transposed), 128x128 tile, BK=32, 4 waves x (4x4) 16x16x32 tiles,
// global_load_lds width-16 staging.
//   MODE 0: C = relu(A@B) -> bf16 hid[z][M][N]
//   MODE 1: fused combine — atomicAdd gate * (A@B) into out[token][col]
// Early-exit on M-strips beyond used[] (claimed slots are [0,used)).
// ---------------------------------------------------------------------------
template <int MODE>
__launch_bounds__(256)
__global__ void gemm_mfma(const ushort_t* __restrict__ A,
                          const ushort_t* __restrict__ Bt,
                          void* __restrict__ Cout,
                          const int* __restrict__ used,
                          const int* __restrict__ s2t,
                          const float* __restrict__ s2g,
                          int egBase, int N, int K) {
    int z = blockIdx.z;
    int eg = egBase + z;
    int row0 = blockIdx.y * 128;
    int col0 = blockIdx.x * 128;
    int bidx = row0 >> 10;            // CAP = 1024
    int rloc = row0 & (CAP - 1);
    if (rloc >= used[eg * BB + bidx]) return;   // unclaimed strip

    __shared__ ushort_t As[128 * 32];   // [m][k], k contiguous
    __shared__ ushort_t Bs[128 * 32];   // [n][k], k contiguous

    int tid = threadIdx.x;
    int lane = tid & 63;
    int wid = tid >> 6;
    int wave_m = (wid & 1) << 6;
    int wave_n = (wid >> 1) << 6;
    int lm = lane & 15;
    int quad = lane >> 4;

    const ushort_t* Aslab = A + (size_t)(MODE == 0 ? eg : z) * MM * K;
    const ushort_t* Bslab = Bt + (size_t)eg * N * K;
    const ushort_t* Ag = Aslab + (size_t)row0 * K;
    const ushort_t* Bg = Bslab + (size_t)col0 * K;

    floatx4 acc[4][4];
#pragma unroll
    for (int i = 0; i < 4; i++)
#pragma unroll
        for (int j = 0; j < 4; j++)
            acc[i][j] = (floatx4)(0.f);

    for (int k0 = 0; k0 < K; k0 += 32) {
        // stage A/B tiles: 512 x 16B chunks each, 2 per thread per tile
#pragma unroll
        for (int it = 0; it < 2; it++) {
            int idx = it * 256 + tid;
            int r = idx >> 2, kc = idx & 3;
            cp16(Ag + (size_t)r * K + k0 + kc * 8, &As[idx * 8]);
            cp16(Bg + (size_t)r * K + k0 + kc * 8, &Bs[idx * 8]);
        }
        __syncthreads();

        bf16x8 af[4], bfr[4];
#pragma unroll
        for (int mt = 0; mt < 4; mt++)
            af[mt] = *(const bf16x8*)&As[(wave_m + mt * 16 + lm) * 32 + quad * 8];
#pragma unroll
        for (int nt = 0; nt < 4; nt++)
            bfr[nt] = *(const bf16x8*)&Bs[(wave_n + nt * 16 + lm) * 32 + quad * 8];
#pragma unroll
        for (int mt = 0; mt < 4; mt++)
#pragma unroll
            for (int nt = 0; nt < 4; nt++)
                acc[mt][nt] = __builtin_amdgcn_mfma_f32_16x16x32_bf16(
                    af[mt], bfr[nt], acc[mt][nt], 0, 0, 0);
        __syncthreads();
    }

    // C/D layout: col = lane&15, row = (lane>>4)*4 + reg  [m89/m91-verified]
    if (MODE == 0) {
        ushort_t* Cs = (ushort_t*)Cout + (size_t)z * MM * N;
#pragma unroll
        for (int mt = 0; mt < 4; mt++) {
            int rbase = row0 + wave_m + mt * 16 + quad * 4;
#pragma unroll
            for (int r = 0; r < 4; r++) {
                int row = rbase + r;
#pragma unroll
                for (int nt = 0; nt < 4; nt++) {
                    int col = col0 + wave_n + nt * 16 + lm;
                    Cs[(size_t)row * N + col] = f2bf(fmaxf(acc[mt][nt][r], 0.f));
                }
            }
        }
    } else {
        float* outp = (float*)Cout;
#pragma unroll
        for (int mt = 0; mt < 4; mt++) {
            int rbase = row0 + wave_m + mt * 16 + quad * 4;
#pragma unroll
            for (int r = 0; r < 4; r++) {
                int row = rbase + r;
                int slot = eg * MM + row;
                int tok = s2t[slot];
                if (tok < 0) continue;
                float g = s2g[slot];
#pragma unroll
                for (int nt = 0; nt < 4; nt++) {
                    int col = col0 + wave_n + nt * 16 + lm;
                    atomicAdd(outp + (size_t)tok * DD + col, g * acc[mt][nt][r]);
                }
            }
        }
    }
}

// ---------------------------------------------------------------------------
// Workspace layout (bytes):
//   0        e1..g2 (6 x 32768)                      = 196,608
//   196608   used  (32 i32, padded)                  = 1,024
//   197632   s2t   (32768 i32)                       = 131,072
//   328704   s2g   (32768 f32)                       = 131,072
//   459776   ein  bf16 [16][2048][512]               = 33,554,432
//   +33.5MB  w1t  bf16 [16][2048(h)][512(d)]         = 33,554,432
//   +67.1MB  w2t  bf16 [16][512(d)][2048(h)]         = 33,554,432
//   +100.6MB hid  bf16 [4][2048][2048] (group of 4)  = 33,554,432
//   total ≈ 134.7 MB (< 151.2 MB proven available)
// ---------------------------------------------------------------------------
extern "C" void kernel_launch(void* const* d_in, const int* in_sizes, int n_in,
                              void* d_out, int out_size, void* d_ws, size_t ws_size,
                              hipStream_t stream) {
    const float* x  = (const float*)d_in[0];
    const float* wg = (const float*)d_in[1];
    const float* w1 = (const float*)d_in[2];
    const float* w2 = (const float*)d_in[3];
    float* out = (float*)d_out;

    char* ws = (char*)d_ws;
    int*      e1   = (int*)(ws);
    int*      e2   = (int*)(ws + 32768);
    int*      p1   = (int*)(ws + 65536);
    int*      p2   = (int*)(ws + 98304);
    float*    g1   = (float*)(ws + 131072);
    float*    g2   = (float*)(ws + 163840);
    int*      used = (int*)(ws + 196608);
    int*      s2t  = (int*)(ws + 197632);
    float*    s2g  = (float*)(ws + 328704);
    ushort_t* ein  = (ushort_t*)(ws + 459776);
    ushort_t* w1t  = (ushort_t*)(ws + 459776 + 1ull * 33554432ull);
    ushort_t* w2t  = (ushort_t*)(ws + 459776 + 2ull * 33554432ull);
    ushort_t* hid  = (ushort_t*)(ws + 459776 + 3ull * 33554432ull);

    hipMemsetAsync(s2t, 0xFF, 131072, stream);                    // all slots -> -1
    hipMemsetAsync(out, 0, (size_t)NTOK * DD * sizeof(float), stream);

    gating_kernel<<<NTOK / 4, 256, 0, stream>>>(x, wg, e1, e2, g1, g2);
    scan_kernel<<<BB * EE, 256, 0, stream>>>(e1, e2, p1, p2, used);
    scatter_kernel<<<NTOK, 128, 0, stream>>>(x, e1, e2, p1, p2, g1, g2, ein, s2t, s2g);
    transpose_bf16<<<dim3(HH / 32, DD / 32, EE), dim3(32, 8), 0, stream>>>(w1, w1t, DD, HH);
    transpose_bf16<<<dim3(DD / 32, HH / 32, EE), dim3(32, 8), 0, stream>>>(w2, w2t, HH, DD);

    for (int g = 0; g < 4; g++) {
        // GEMM1: ein[eg] (2048x512) @ w1[eg] (512x2048) -> relu -> hid bf16
        gemm_mfma<0><<<dim3(HH / 128, MM / 128, 4), 256, 0, stream>>>(
            ein, w1t, hid, used, nullptr, nullptr, g * 4, HH, DD);
        // GEMM2: hid (2048x2048) @ w2[eg] (2048x512) -> gate-weighted scatter-add
        gemm_mfma<1><<<dim3(DD / 128, MM / 128, 4), 256, 0, stream>>>(
            hid, w2t, out, used, s2t, s2g, g * 4, DD, HH);
    }
}

// Round 3
// 378.475 us; speedup vs baseline: 8.3074x; 1.3957x over previous
//
#include <hip/hip_runtime.h>

// Problem constants (from reference setup_inputs)
#define BB 2
#define NN 4096
#define DD 512
#define EE 16
#define HH 2048
#define CAP 1024            // capacity = int((4096*2)*2.0/16) = 1024
#define NTOK (BB*NN)        // 8192
#define MM (BB*CAP)         // 2048 = per-expert logical M
#define MAXSTRIP 160        // >= worst-case active 128-row strips (<=159)

typedef unsigned short ushort_t;
typedef __attribute__((ext_vector_type(8))) short bf16x8;   // 8 bf16 = 4 VGPRs
typedef __attribute__((ext_vector_type(4))) float floatx4;  // MFMA accumulator

// round-to-nearest-even f32 -> bf16 bit pattern
__device__ __forceinline__ ushort_t f2bf(float f) {
    union { float f; unsigned u; } v; v.f = f;
    unsigned r = v.u + 0x7fffu + ((v.u >> 16) & 1u);
    return (ushort_t)(r >> 16);
}

// async global->LDS, 16B per lane (global_load_lds_dwordx4).
// LDS side must be wave-uniform base + lane*16 (lane-linear) — all swizzling
// is applied to the per-lane GLOBAL address instead.
__device__ __forceinline__ void cp16(const void* g, void* l) {
    __builtin_amdgcn_global_load_lds(
        (const __attribute__((address_space(1))) void*)g,
        (__attribute__((address_space(3))) void*)l, 16, 0, 0);
}

// ---------------------------------------------------------------------------
// Kernel 1: gating — logits = x @ w_gating, softmax, top-2, normalized gates.
// One wave per token (f32 exact: selection must match reference argmax).
// ---------------------------------------------------------------------------
__launch_bounds__(256)
__global__ void gating_kernel(const float* __restrict__ x,
                              const float* __restrict__ wg,
                              int* __restrict__ e1, int* __restrict__ e2,
                              float* __restrict__ g1, float* __restrict__ g2) {
    int wave = threadIdx.x >> 6;
    int lane = threadIdx.x & 63;
    int t = blockIdx.x * 4 + wave;
    const float* xp = x + (size_t)t * DD;

    float acc[EE];
#pragma unroll
    for (int e = 0; e < EE; e++) acc[e] = 0.f;
    for (int d = lane; d < DD; d += 64) {
        float xv = xp[d];
        const float* wrow = wg + d * EE;
#pragma unroll
        for (int e = 0; e < EE; e++) acc[e] = fmaf(xv, wrow[e], acc[e]);
    }
#pragma unroll
    for (int off = 32; off > 0; off >>= 1) {
#pragma unroll
        for (int e = 0; e < EE; e++) acc[e] += __shfl_xor(acc[e], off, 64);
    }
    if (lane == 0) {
        float m = acc[0];
#pragma unroll
        for (int e = 1; e < EE; e++) m = fmaxf(m, acc[e]);
        float p[EE]; float s = 0.f;
#pragma unroll
        for (int e = 0; e < EE; e++) { p[e] = __expf(acc[e] - m); s += p[e]; }
        float inv = 1.f / s;
#pragma unroll
        for (int e = 0; e < EE; e++) p[e] *= inv;
        int i1 = 0; float v1 = p[0];
#pragma unroll
        for (int e = 1; e < EE; e++) if (p[e] > v1) { v1 = p[e]; i1 = e; }
        int i2 = (i1 == 0) ? 1 : 0; float v2 = p[i2];
#pragma unroll
        for (int e = 0; e < EE; e++)
            if (e != i1 && p[e] > v2) { v2 = p[e]; i2 = e; }
        float denom = v1 + v2 + 1e-9f;
        e1[t] = i1; e2[t] = i2;
        g1[t] = v1 / denom; g2[t] = v2 / denom;
    }
}

// ---------------------------------------------------------------------------
// Kernel 2: per-(b,e) exclusive scan over token order -> slot assignment with
// capacity drop. Writes slot->token (s2t), slot->gate (s2g), used[e][b].
// s2t pre-memset to -1; claimed slots are contiguous [0, used).
// ---------------------------------------------------------------------------
__launch_bounds__(256)
__global__ void scan_kernel(const int* __restrict__ e1, const int* __restrict__ e2,
                            const float* __restrict__ g1, const float* __restrict__ g2,
                            int* __restrict__ s2t, float* __restrict__ s2g,
                            int* __restrict__ used) {
    int b = blockIdx.x / EE;
    int e = blockIdx.x % EE;
    int tid = threadIdx.x;
    const int base = b * NN;
    int n0 = tid * 16;

    unsigned m1 = 0, m2 = 0;
    int c1 = 0, c2 = 0;
#pragma unroll
    for (int j = 0; j < 16; j++) {
        int n = n0 + j;
        if (e1[base + n] == e) { m1 |= 1u << j; c1++; }
        if (e2[base + n] == e) { m2 |= 1u << j; c2++; }
    }
    __shared__ int s1[256], s2[256];
    s1[tid] = c1; s2[tid] = c2;
    __syncthreads();
    for (int off = 1; off < 256; off <<= 1) {
        int a1 = (tid >= off) ? s1[tid - off] : 0;
        int a2 = (tid >= off) ? s2[tid - off] : 0;
        __syncthreads();
        s1[tid] += a1; s2[tid] += a2;
        __syncthreads();
    }
    int total1 = s1[255];
    int total2 = s2[255];
    int kept1 = min(total1, CAP);
    int ex1 = s1[tid] - c1;
    int ex2 = s2[tid] - c2 + kept1;
    const int sbase = (e * BB + b) * CAP;
#pragma unroll
    for (int j = 0; j < 16; j++) {
        int n = n0 + j;
        if (m1 & (1u << j)) {
            if (ex1 < CAP) { s2t[sbase + ex1] = base + n; s2g[sbase + ex1] = g1[base + n]; }
            ex1++;
        }
        if (m2 & (1u << j)) {
            if (ex2 < CAP) { s2t[sbase + ex2] = base + n; s2g[sbase + ex2] = g2[base + n]; }
            ex2++;
        }
    }
    if (tid == 255) {
        int kept2 = min(total2, max(0, CAP - kept1));
        used[e * BB + b] = kept1 + kept2;
    }
}

// ---------------------------------------------------------------------------
// Kernel 3: x (f32) -> xbf (bf16), contiguous. GEMM1 gathers rows from here.
// ---------------------------------------------------------------------------
__launch_bounds__(256)
__global__ void xbf_kernel(const float* __restrict__ x, ushort_t* __restrict__ xbf) {
    int i = blockIdx.x * 256 + threadIdx.x;      // float4 index, 1M total
    float4 v = ((const float4*)x)[i];
    ushort4 h;
    h.x = f2bf(v.x); h.y = f2bf(v.y); h.z = f2bf(v.z); h.w = f2bf(v.w);
    ((ushort4*)xbf)[i] = h;
}

// ---------------------------------------------------------------------------
// Kernel 4: build the active-strip worklist. Entry = (e<<16)|ytile; strip id
// (= compact hid row block) is the entry's position. wl[MAXSTRIP] = count.
// ---------------------------------------------------------------------------
__global__ void worklist_kernel(const int* __restrict__ used, int* __restrict__ wl) {
    __shared__ int ns[32], pre[32];
    int i = threadIdx.x;
    if (i < 32) {
        int e = i >> 1, b = i & 1;
        ns[i] = (used[e * BB + b] + 127) >> 7;
    }
    __syncthreads();
    if (i == 0) {
        int acc = 0;
        for (int j = 0; j < 32; j++) { pre[j] = acc; acc += ns[j]; }
        wl[MAXSTRIP] = acc;
    }
    __syncthreads();
    if (i < 32) {
        int e = i >> 1, b = i & 1;
        int p = pre[i];
        for (int s = 0; s < ns[i]; s++)
            wl[p + s] = (e << 16) | (b * 8 + s);
    }
}

// ---------------------------------------------------------------------------
// Kernel 5: per-expert transpose + bf16: in f32 [E][R][C] -> out bf16 [E][C][R].
// ---------------------------------------------------------------------------
__global__ void transpose_bf16(const float* __restrict__ in,
                               ushort_t* __restrict__ outp, int R, int C) {
    __shared__ float tile[32][33];
    const float* slab = in + (size_t)blockIdx.z * R * C;
    ushort_t* oslab = outp + (size_t)blockIdx.z * R * C;
    int c0 = blockIdx.x * 32, r0 = blockIdx.y * 32;
    int tx = threadIdx.x, ty = threadIdx.y;   // (32, 8)
#pragma unroll
    for (int j = 0; j < 4; j++)
        tile[ty + j * 8][tx] = slab[(size_t)(r0 + ty + j * 8) * C + c0 + tx];
    __syncthreads();
#pragma unroll
    for (int j = 0; j < 4; j++)
        oslab[(size_t)(c0 + ty + j * 8) * R + r0 + tx] = f2bf(tile[tx][ty + j * 8]);
}

// ---------------------------------------------------------------------------
// Kernel 6: bf16 MFMA GEMM over worklist strips. 128x128 tile, BK=32,
// 4 waves x (4x4) 16x16x32 MFMA. global_load_lds width-16 staging with
// XOR-swizzled (on the global side) chunk columns -> 2-way-max LDS banking.
//   MODE 0 (GEMM1): A rows gathered from xbf via s2t (K=512), B=w1t,
//                   writes relu -> hid[strip] (compact, N=2048, bf16).
//   MODE 1 (GEMM2): A = hid[strip] (K=2048, split-K=2 via blockIdx.z),
//                   B=w2t, epilogue scatters gate*acc into out via atomicAdd.
// ---------------------------------------------------------------------------
template <int MODE>
__launch_bounds__(256)
__global__ void gemm_mfma(const ushort_t* __restrict__ Abase,
                          const ushort_t* __restrict__ Bt,
                          void* __restrict__ Cout,
                          const int* __restrict__ wl,
                          const int* __restrict__ s2t,
                          const float* __restrict__ s2g) {
    int wi = blockIdx.y;
    if (wi >= wl[MAXSTRIP]) return;
    int entry = wl[wi];
    int e = entry >> 16;
    int ytile = entry & 0xffff;

    const int N = (MODE == 0) ? HH : DD;      // B slab rows
    const int K = (MODE == 0) ? DD : HH;      // B slab K (full)
    const int kIters = (MODE == 0) ? (DD / 32) : (HH / 2 / 32);
    int col0 = blockIdx.x * 128;
    int kOff = (MODE == 0) ? 0 : blockIdx.z * (HH / 2);

    __shared__ ushort_t As[128 * 32];
    __shared__ ushort_t Bs[128 * 32];

    int tid = threadIdx.x;
    int lane = tid & 63;
    int wid = tid >> 6;
    int wave_m = (wid & 1) << 6;
    int wave_n = (wid >> 1) << 6;
    int lm = lane & 15;
    int quad = lane >> 4;
    // fragment-read swizzle: global chunk (r, q) lives at LDS col q ^ ((r>>1)&3)
    int sw = (quad ^ ((lm >> 1) & 3)) * 8;

    // staging geometry: lane handles LDS chunks idx = {tid, 256+tid};
    // r = idx>>2, stored col = idx&3, global col c = (idx&3) ^ ((idx>>3)&3)
    const ushort_t* aptr[2];
    const ushort_t* bptr[2];
    bool aval[2];
#pragma unroll
    for (int it = 0; it < 2; it++) {
        int idx = it * 256 + tid;
        int r = idx >> 2;
        int c = (idx & 3) ^ ((idx >> 3) & 3);
        if (MODE == 0) {
            int tok = s2t[e * MM + ytile * 128 + r];
            aval[it] = (tok >= 0);
            aptr[it] = Abase + (size_t)(tok < 0 ? 0 : tok) * DD + c * 8;
        } else {
            aval[it] = true;
            aptr[it] = Abase + (size_t)(wi * 128 + r) * HH + kOff + c * 8;
        }
        bptr[it] = Bt + (size_t)e * N * K + (size_t)(col0 + r) * K + kOff + c * 8;
    }

    floatx4 acc[4][4];
#pragma unroll
    for (int i = 0; i < 4; i++)
#pragma unroll
        for (int j = 0; j < 4; j++)
            acc[i][j] = (floatx4)(0.f);

    for (int ki = 0; ki < kIters; ki++) {
#pragma unroll
        for (int it = 0; it < 2; it++) {
            int idx = it * 256 + tid;
            if (aval[it]) cp16(aptr[it], &As[idx * 8]);
            cp16(bptr[it], &Bs[idx * 8]);
            aptr[it] += 32; bptr[it] += 32;
        }
        __syncthreads();

        bf16x8 af[4], bfr[4];
#pragma unroll
        for (int mt = 0; mt < 4; mt++)
            af[mt] = *(const bf16x8*)&As[(wave_m + mt * 16 + lm) * 32 + sw];
#pragma unroll
        for (int nt = 0; nt < 4; nt++)
            bfr[nt] = *(const bf16x8*)&Bs[(wave_n + nt * 16 + lm) * 32 + sw];
#pragma unroll
        for (int mt = 0; mt < 4; mt++)
#pragma unroll
            for (int nt = 0; nt < 4; nt++)
                acc[mt][nt] = __builtin_amdgcn_mfma_f32_16x16x32_bf16(
                    af[mt], bfr[nt], acc[mt][nt], 0, 0, 0);
        __syncthreads();
    }

    // C/D layout: col = lane&15, row = (lane>>4)*4 + reg  [m89/m91-verified]
    if (MODE == 0) {
        ushort_t* hp = (ushort_t*)Cout + (size_t)wi * 128 * HH;
#pragma unroll
        for (int mt = 0; mt < 4; mt++) {
#pragma unroll
            for (int r = 0; r < 4; r++) {
                int row = wave_m + mt * 16 + quad * 4 + r;
#pragma unroll
                for (int nt = 0; nt < 4; nt++) {
                    int col = col0 + wave_n + nt * 16 + lm;
                    hp[(size_t)row * HH + col] = f2bf(fmaxf(acc[mt][nt][r], 0.f));
                }
            }
        }
    } else {
        float* outp = (float*)Cout;
#pragma unroll
        for (int mt = 0; mt < 4; mt++) {
#pragma unroll
            for (int r = 0; r < 4; r++) {
                int row = wave_m + mt * 16 + quad * 4 + r;
                int slot = e * MM + ytile * 128 + row;
                int tok = s2t[slot];
                if (tok < 0) continue;
                float g = s2g[slot];
#pragma unroll
                for (int nt = 0; nt < 4; nt++) {
                    int col = col0 + wave_n + nt * 16 + lm;
                    atomicAdd(outp + (size_t)tok * DD + col, g * acc[mt][nt][r]);
                }
            }
        }
    }
}

// ---------------------------------------------------------------------------
// Workspace layout (bytes), total 126,224,384 (< 151.2 MB proven):
//   0         e1 32768 | 32768 e2 | 65536 g1 | 98304 g2
//   131072    used (pad 1024)
//   132096    wl   (161 ints, pad 1024)
//   133120    s2t  131072
//   264192    s2g  131072
//   395264    xbf  bf16 [8192][512]            =  8,388,608
//   8783872   wt   bf16 (w1t, then w2t)        = 33,554,432
//   42338304  hid  bf16 [160 strips][128][2048]= 83,886,080
// ---------------------------------------------------------------------------
extern "C" void kernel_launch(void* const* d_in, const int* in_sizes, int n_in,
                              void* d_out, int out_size, void* d_ws, size_t ws_size,
                              hipStream_t stream) {
    const float* x  = (const float*)d_in[0];
    const float* wg = (const float*)d_in[1];
    const float* w1 = (const float*)d_in[2];
    const float* w2 = (const float*)d_in[3];
    float* out = (float*)d_out;

    char* ws = (char*)d_ws;
    int*      e1   = (int*)(ws);
    int*      e2   = (int*)(ws + 32768);
    float*    g1   = (float*)(ws + 65536);
    float*    g2   = (float*)(ws + 98304);
    int*      used = (int*)(ws + 131072);
    int*      wl   = (int*)(ws + 132096);
    int*      s2t  = (int*)(ws + 133120);
    float*    s2g  = (float*)(ws + 264192);
    ushort_t* xbf  = (ushort_t*)(ws + 395264);
    ushort_t* wt   = (ushort_t*)(ws + 8783872);
    ushort_t* hid  = (ushort_t*)(ws + 42338304);

    hipMemsetAsync(s2t, 0xFF, 131072, stream);                    // slots -> -1
    hipMemsetAsync(out, 0, (size_t)NTOK * DD * sizeof(float), stream);

    gating_kernel<<<NTOK / 4, 256, 0, stream>>>(x, wg, e1, e2, g1, g2);
    scan_kernel<<<BB * EE, 256, 0, stream>>>(e1, e2, g1, g2, s2t, s2g, used);
    xbf_kernel<<<NTOK * DD / 4 / 256, 256, 0, stream>>>(x, xbf);
    worklist_kernel<<<1, 64, 0, stream>>>(used, wl);

    // GEMM1: gather(xbf) @ w1t -> relu -> hid (compact strips)
    transpose_bf16<<<dim3(HH / 32, DD / 32, EE), dim3(32, 8), 0, stream>>>(w1, wt, DD, HH);
    gemm_mfma<0><<<dim3(HH / 128, MAXSTRIP), 256, 0, stream>>>(xbf, wt, hid, wl, s2t, s2g);

    // GEMM2: hid @ w2t -> gate-weighted scatter-add into out (split-K = 2)
    transpose_bf16<<<dim3(DD / 32, HH / 32, EE), dim3(32, 8), 0, stream>>>(w2, wt, HH, DD);
    gemm_mfma<1><<<dim3(DD / 128, MAXSTRIP, 2), 256, 0, stream>>>(hid, wt, out, wl, s2t, s2g);
}